// Round 3
// baseline (1602.804 us; speedup 1.0000x reference)
//
#include <hip/hip_runtime.h>
#include <math.h>

#define BATCH 8
#define WID   32
#define NX    64
#define NY    64
#define NT    40
#define M1C   12
#define KT    8      // M3
#define KXC   24
#define KYC   24
#define NXY   (NX*NY)        // 4096
#define NXYT  (NXY*NT)       // 163840
#define NP    (BATCH*NXYT)   // 1310720

#define TWO_PI 6.283185307179586f

static __device__ __forceinline__ float gelu_f(float v){
  return 0.5f*v*(1.0f + erff(v*0.7071067811865476f));
}

// barrier that does NOT drain vmcnt (keeps global prefetch loads in flight).
static __device__ __forceinline__ void barrier_lds(){
  asm volatile("s_waitcnt lgkmcnt(0)\n\ts_barrier" ::: "memory");
}

// V layout throughout: [b][x][y][t][c]  (channel-innermost, plane = 1280 floats)

// ---------------- fc0: [B,X,Y,T,5] -> V ----------------
__global__ __launch_bounds__(256) void k_fc0(const float* __restrict__ h, const float* __restrict__ x,
                                             const float* __restrict__ w, const float* __restrict__ b,
                                             float* __restrict__ V){
  __shared__ float sw[160], sb[32];
  int tid=threadIdx.x;
  if(tid<160) sw[tid]=w[tid];
  if(tid<32)  sb[tid]=b[tid];
  __syncthreads();
  int pl = tid>>3, q = tid&7;
  int p = blockIdx.x*32 + pl;
  float i0=h[(size_t)p*2], i1=h[(size_t)p*2+1];
  float i2=x[(size_t)p*3], i3=x[(size_t)p*3+1], i4=x[(size_t)p*3+2];
  int c0=q*4;
  float4 o;
  float* po=(float*)&o;
  #pragma unroll
  for(int u=0;u<4;u++){
    int c=c0+u;
    po[u] = sb[c] + i0*sw[c] + i1*sw[32+c] + i2*sw[64+c] + i3*sw[96+c] + i4*sw[128+c];
  }
  ((float4*)V)[(size_t)p*8 + q] = o;
}

// ------- fused forward T+Y per (b,x,ky-half): V slice -> F2 partial -------
// R8: ky-split x2 (grid 512->1024: 2->4 blocks/CU; disjoint F2 outputs, no
// reduction); radix-2 T-DFT butterfly (w^{t+20} = (-1)^k w^t: T-DFT VALU
// 320->120 per 2y, twr 80->40 VGPR); LDS 61.7KB->26.6KB (4-y staging groups)
// so LDS no longer caps occupancy. Split lands on the M1C=12 boundary.
__global__ __launch_bounds__(256) void k_fwd_ty(const float* __restrict__ V, float2* __restrict__ F2){
  __shared__ __align__(16) unsigned char smem[26624];
  float*  vt    = (float*)smem;                 // 4 y-planes: 5120 floats, 20480 B
  float2* twy   = (float2*)(smem + 20480);      // [12][64] = 6144 B (end 26624)
  float2* f2out = (float2*)smem;                // epilogue alias: 32*97*8 = 24832 B (twy dead)
  int tid = threadIdx.x;
  int b = blockIdx.x >> 7, x = (blockIdx.x >> 1) & 63, kyh = blockIdx.x & 1;
  int c = tid & 31, k = tid >> 5;
  // twiddle table for this block's 12 ky modes
  for(int i=tid;i<12*NY;i+=256){
    int kyl=i>>6, y=i&63;
    int ky = kyh*12 + kyl;
    int f = ky<M1C ? ky : ky+40;
    float ang = -TWO_PI*(float)((f*y)%NY)/(float)NY;
    twy[i] = make_float2(cosf(ang), sinf(ang));
  }
  // per-thread T-twiddle HALF-row (radix-2: t and t+20 share a twiddle up to sign)
  float2 twr[20];
  #pragma unroll
  for(int t=0;t<20;t++){
    float ang = -TWO_PI*(float)((k*t)%NT)/(float)NT;
    twr[t] = make_float2(cosf(ang), sinf(ang));
  }
  float sgn = (k&1) ? -1.0f : 1.0f;
  float2 acc[12];
  #pragma unroll
  for(int q=0;q<12;q++) acc[q]=make_float2(0.f,0.f);
  const float4* src = (const float4*)(V + (size_t)(b*NX+x)*(NY*NT*WID));
  for(int g=0; g<16; g++){
    __syncthreads();                       // prev compute done (vt reuse safe)
    #pragma unroll
    for(int r=0;r<5;r++) ((float4*)vt)[r*256+tid] = src[g*1280 + r*256 + tid];
    __syncthreads();
    #pragma unroll
    for(int yl=0; yl<4; yl+=2){
      float sr0=0.f, si0=0.f, sr1=0.f, si1=0.f;
      const float* vp0 = vt + yl*1280 + c;
      const float* vp1 = vp0 + 1280;
      #pragma unroll
      for(int t=0;t<20;t++){
        float2 w = twr[t];
        float u0 = fmaf(sgn, vp0[(t+20)*32], vp0[t*32]);   // radix-2 butterfly
        float u1 = fmaf(sgn, vp1[(t+20)*32], vp1[t*32]);
        sr0 += u0*w.x; si0 += u0*w.y;
        sr1 += u1*w.x; si1 += u1*w.y;
      }
      int y = g*4 + yl;
      #pragma unroll
      for(int q=0;q<12;q++){
        float4 wy = *(const float4*)&twy[q*NY + y];   // (w_y, w_{y+1}) one b128
        acc[q].x += sr0*wy.x - si0*wy.y + sr1*wy.z - si1*wy.w;
        acc[q].y += sr0*wy.y + si0*wy.x + sr1*wy.w + si1*wy.z;
      }
    }
  }
  __syncthreads();                         // vt/twy dead -> f2out alias safe
  #pragma unroll
  for(int q=0;q<12;q++) f2out[c*97 + q*8 + k] = acc[q];
  __syncthreads();
  for(int i=tid;i<WID*96;i+=256){
    int cc=i/96, e=i-cc*96;
    F2[((size_t)(b*WID+cc)*NX + x)*(KYC*KT) + kyh*96 + e] = f2out[cc*97 + e];
  }
}

// ---------------- forward X: F2 -> F3 [B,32,24,24,8] cplx ----------------
__global__ __launch_bounds__(256) void k_fwd_x(const float2* __restrict__ F2, float2* __restrict__ F3){
  __shared__ float2 tile[NX*KT];
  __shared__ float2 twi[KXC*65];          // stride 65 cplx
  int tid=threadIdx.x;
  int bc = blockIdx.x / KYC;
  int ky = blockIdx.x - bc*KYC;
  for(int i=tid;i<NX*KT;i+=256){
    int xx=i/KT, kt=i-xx*KT;
    tile[i] = F2[((size_t)bc*NX + xx)*(KYC*KT) + ky*KT + kt];
  }
  for(int i=tid;i<KXC*NX;i+=256){
    int kx=i/NX, xx=i-kx*NX;
    int f = kx<M1C ? kx : kx+40;
    float ang = -TWO_PI*(float)((f*xx)%NX)/(float)NX;
    twi[kx*65+xx] = make_float2(cosf(ang), sinf(ang));
  }
  __syncthreads();
  for(int item=tid; item<KXC*KT; item+=256){
    int kx=item/KT, kt=item-kx*KT;
    float sr=0.f, si=0.f;
    #pragma unroll 8
    for(int xx=0;xx<NX;xx++){
      float2 a = tile[xx*KT+kt];
      float2 w = twi[kx*65+xx];
      sr += a.x*w.x - a.y*w.y;
      si += a.x*w.y + a.y*w.x;
    }
    F3[(size_t)bc*(KXC*KYC*KT) + kx*(KYC*KT) + ky*KT + kt] = make_float2(sr,si);
  }
}

// ---------------- channel mix: F3 -> F4 ----------------
__global__ __launch_bounds__(256) void k_mix(const float2* __restrict__ F3, const float* __restrict__ wr,
                                             const float* __restrict__ wi, float2* __restrict__ F4){
  __shared__ float2 f3s[BATCH*WID*KT];     // [b][i][kt] = 16 KB
  int tid = threadIdx.x;
  int kx = blockIdx.x / KYC, ky = blockIdx.x - kx*KYC;
  int mode0 = blockIdx.x * KT;
  int xp = (kx>=M1C), yp = (ky>=M1C);
  int m1 = kx - M1C*xp, m2 = ky - M1C*yp;
  int blk = xp + 2*yp;
  for(int i=tid;i<1024;i+=256){
    int row=i>>2, q=i&3;
    ((float4*)f3s)[row*4+q] = ((const float4*)(F3 + (size_t)row*4608 + mode0))[q];
  }
  int o = tid>>3, kt = tid&7;
  size_t wbase = (size_t)blk*1179648 + (size_t)o*1152 + m1*96 + m2*8 + kt;
  float wre[WID], wim[WID];
  #pragma unroll
  for(int i=0;i<WID;i++){
    wre[i] = wr[wbase + (size_t)i*36864];
    wim[i] = wi[wbase + (size_t)i*36864];
  }
  __syncthreads();
  #pragma unroll
  for(int b=0;b<BATCH;b++){
    float ar=0.f, ai=0.f;
    #pragma unroll
    for(int i=0;i<WID;i++){
      float2 a = f3s[(b*WID+i)*KT + kt];
      ar += a.x*wre[i] - a.y*wim[i];
      ai += a.x*wim[i] + a.y*wre[i];
    }
    F4[(size_t)(b*WID+o)*4608 + mode0 + kt] = make_float2(ar,ai);
  }
}

// ---------------- inverse X: F4 -> F2 (1/64 folded) ----------------
__global__ __launch_bounds__(256) void k_inv_x(const float2* __restrict__ F4, float2* __restrict__ F2){
  __shared__ float2 tile[KXC*KT];
  __shared__ float2 twi[NX*25];
  int tid=threadIdx.x;
  int bc = blockIdx.x / KYC, ky = blockIdx.x - (blockIdx.x/KYC)*KYC;
  for(int i=tid;i<KXC*KT;i+=256){
    int kx=i/KT, kt=i-kx*KT;
    tile[i] = F4[(size_t)bc*4608 + kx*(KYC*KT) + ky*KT + kt];
  }
  for(int i=tid;i<NX*KXC;i+=256){
    int xx=i/KXC, kx=i-xx*KXC;
    int f = kx<M1C ? kx : kx+40;
    float ang = TWO_PI*(float)((f*xx)%NX)/(float)NX;
    twi[xx*25+kx] = make_float2(cosf(ang)*(1.0f/64.0f), sinf(ang)*(1.0f/64.0f));
  }
  __syncthreads();
  for(int item=tid; item<NX*KT; item+=256){
    int xx=item/KT, kt=item-xx*KT;
    float sr=0.f, si=0.f;
    #pragma unroll 8
    for(int kx=0;kx<KXC;kx++){
      float2 a = tile[kx*KT+kt];
      float2 w = twi[xx*25+kx];
      sr += a.x*w.x - a.y*w.y;
      si += a.x*w.y + a.y*w.x;
    }
    F2[((size_t)bc*NX + xx)*(KYC*KT) + ky*KT + kt] = make_float2(sr,si);
  }
}

// ------- fused inv-Y + irfft-T + conv1x1 [+gelu], in-place on V -------
// grid = B*NX*2, block = (b, x, y-half). NOTE: no min-waves clamp — the kernel
// needs ~110 VGPRs (fr[24]c + wreg[32] + 2-deep prefetch); clamping forced
// VGPR=64 and spilled fr/wreg to scratch (R3-R5 bug).
// R6/R7 established: wall is NOT VALU count / LDS count / barrier count;
// grid-capped at 4 blocks/CU, latency-bound. Left as-is (R7 schedule).
template<bool GELU>
__global__ __launch_bounds__(256) void k_conv(const float2* __restrict__ F2, const float* __restrict__ wcv,
                                              const float* __restrict__ bcv, float* __restrict__ V){
  __shared__ __align__(16) unsigned char smem[34816];
  float*  vtA  = (float*)smem;                  // [2][1280] = 10240 B
  float*  vtB  = (float*)(smem+10240);          // [2][1280] = 10240 B
  float2* ftc0 = (float2*)(smem+20480);         // [2][256]  =  4096 B
  float2* ftc1 = (float2*)(smem+24576);         // [2][256]  =  4096 B
  float2* twy  = (float2*)(smem+28672);         // [32][24]  =  6144 B (end 34816)
  float2* f2h  = (float2*)smem;                 // prologue alias: 24576 B

  int tid=threadIdx.x;
  int b  = blockIdx.x >> 7;
  int x  = (blockIdx.x >> 1) & 63;
  int y0 = (blockIdx.x & 1) * 32;
  int cid = tid & 31, ktid = tid >> 5;   // inv-Y identity
  int oid = tid & 31, tg  = tid >> 5;    // conv identity; t = tg*5+j

  // ---- prologue: F2 slice -> registers via LDS (two halves) ----
  float2 fr[KYC];
  #pragma unroll
  for(int half=0; half<2; half++){
    for(int i=tid;i<1536;i+=256){
      int cc=i/96, q=i-cc*96;
      ((float4*)f2h)[i] = *((const float4*)(F2 + ((size_t)(b*WID + half*16 + cc)*NX + x)*(KYC*KT)) + q);
    }
    __syncthreads();
    if((cid>>4) == half){
      const float2* fp = f2h + (cid&15)*192 + ktid;
      #pragma unroll
      for(int ky=0;ky<KYC;ky++) fr[ky] = fp[ky*8];
    }
    __syncthreads();
  }
  // fold irfft-T scale (k==0?1:2)/NT into fr (linear through inv-Y)
  {
    float ts = (ktid==0 ? 1.0f : 2.0f) * (1.0f/(float)NT);
    #pragma unroll
    for(int ky=0;ky<KYC;ky++){ fr[ky].x *= ts; fr[ky].y *= ts; }
  }
  float wreg[WID];
  #pragma unroll
  for(int cc=0;cc<WID;cc++) wreg[cc] = wcv[oid*WID + cc];
  float breg = bcv[oid];
  // per-thread T-twiddle base: e^{i*pi/4*(k*tg mod 8)}  (t = 5*tg + j)
  float2 twtg[KT];
  #pragma unroll
  for(int k=0;k<KT;k++){
    float ang = 0.78539816339744831f*(float)((k*tg)&7);
    twtg[k] = make_float2(cosf(ang), sinf(ang));
  }
  for(int i=tid;i<32*KYC;i+=256){
    int yy=i/KYC, ky=i-yy*KYC;
    int f = ky<M1C ? ky : ky+40;
    float ang = TWO_PI*(float)((f*(y0+yy))%NY)/(float)NY;
    twy[i] = make_float2(cosf(ang)*(1.0f/64.0f), sinf(ang)*(1.0f/64.0f));
  }
  float* plane = V + (size_t)((b*NX+x)*NY + y0)*(NT*WID);
  const float4* gp = (const float4*)plane;
  bool has3 = tid < 128;
  // stage pair 0 into vtA
  {
    float4 p0 = gp[tid], p1 = gp[256+tid];
    float4 p2 = has3 ? gp[512+tid] : make_float4(0,0,0,0);
    ((float4*)vtA)[tid] = p0;
    ((float4*)vtA)[256+tid] = p1;
    if(has3) ((float4*)vtA)[512+tid] = p2;
  }
  // pair 1 -> registers (stays in flight across the prologue barrier's drain)
  float4 rA = gp[640+tid], rB = gp[640+256+tid];
  float4 rC = has3 ? gp[640+512+tid] : make_float4(0,0,0,0);
  __syncthreads();                        // publish vtA + twy (prologue only)

  // cos/sin(pi*k*j/20) — compile-time literals (fold into v_fmac immediates)
  constexpr float CJ[KT][5] = {
    {1.f, 1.f,          1.f,          1.f,          1.f         },
    {1.f, 0.98768834f,  0.95105652f,  0.89100652f,  0.80901699f },
    {1.f, 0.95105652f,  0.80901699f,  0.58778525f,  0.30901699f },
    {1.f, 0.89100652f,  0.58778525f,  0.15643447f, -0.30901699f },
    {1.f, 0.80901699f,  0.30901699f, -0.30901699f, -0.80901699f },
    {1.f, 0.70710678f,  0.f,         -0.70710678f, -1.f         },
    {1.f, 0.58778525f, -0.30901699f, -0.95105652f, -0.80901699f },
    {1.f, 0.45399050f, -0.58778525f, -0.98768834f, -0.30901699f },
  };
  constexpr float SJ[KT][5] = {
    {0.f, 0.f,          0.f,          0.f,          0.f         },
    {0.f, 0.15643447f,  0.30901699f,  0.45399050f,  0.58778525f },
    {0.f, 0.30901699f,  0.58778525f,  0.80901699f,  0.95105652f },
    {0.f, 0.45399050f,  0.80901699f,  0.98768834f,  0.95105652f },
    {0.f, 0.58778525f,  0.95105652f,  0.95105652f,  0.58778525f },
    {0.f, 0.70710678f,  1.f,          0.70710678f,  0.f         },
    {0.f, 0.80901699f,  0.95105652f,  0.30901699f, -0.58778525f },
    {0.f, 0.89100652f,  0.80901699f, -0.15643447f, -0.95105652f },
  };

  #pragma unroll 1
  for(int it=0; it<16; ++it){
    float*  vcur = (it&1) ? vtB  : vtA;
    float*  vnxt = (it&1) ? vtA  : vtB;
    float2* fcur = (it&1) ? ftc1 : ftc0;
    int yl = it*2;
    { // inverse-Y for y=yl and yl+1, interleaved chains, b128 ky-pair twiddles
      const float2* tw0 = twy + (size_t)yl*KYC;
      const float2* tw1 = tw0 + KYC;
      float sr0=0.f, si0=0.f, sr1=0.f, si1=0.f;
      #pragma unroll
      for(int ky=0;ky<KYC;ky+=2){
        float2 a  = fr[ky];
        float2 b2 = fr[ky+1];
        float4 w0 = *(const float4*)&tw0[ky];
        float4 w1 = *(const float4*)&tw1[ky];
        sr0 += a.x*w0.x - a.y*w0.y + b2.x*w0.z - b2.y*w0.w;
        si0 += a.x*w0.y + a.y*w0.x + b2.x*w0.w + b2.y*w0.z;
        sr1 += a.x*w1.x - a.y*w1.y + b2.x*w1.z - b2.y*w1.w;
        si1 += a.x*w1.y + a.y*w1.x + b2.x*w1.w + b2.y*w1.z;
      }
      fcur[      ktid*32 + cid] = make_float2(sr0,si0);
      fcur[256 + ktid*32 + cid] = make_float2(sr1,si1);
    }
    barrier_lds();                        // the ONLY barrier per iteration
    // stage pair it+1 (regs -> vnxt) BEFORE this iteration's stores; the
    // vmcnt wait here only drains rA/rB/rC (issued a full iteration ago).
    if(it+1 < 16){
      ((float4*)vnxt)[tid] = rA;
      ((float4*)vnxt)[256+tid] = rB;
      if(has3) ((float4*)vnxt)[512+tid] = rC;
    }
    if(it+2 < 16){                        // issue loads for pair it+2
      const float4* q = gp + (size_t)(it+2)*640;
      rA = q[tid]; rB = q[256+tid];
      if(has3) rC = q[512+tid];
    }
    #pragma unroll
    for(int yy=0; yy<2; yy++){            // conv1x1 + irfft-T for the two y
      const float2* fsrc = fcur + yy*256;
      const float*  vb   = vcur + yy*1280;
      float* outp = plane + (size_t)(yl+yy)*(NT*WID);
      float acc[5];
      #pragma unroll
      for(int j=0;j<5;j++) acc[j] = breg;
      #pragma unroll
      for(int k=0;k<KT;k++){              // rotate mode by twtg, then literal DFT
        float2 f = fsrc[k*32 + oid];
        float gx = f.x*twtg[k].x - f.y*twtg[k].y;
        float gy = f.x*twtg[k].y + f.y*twtg[k].x;
        #pragma unroll
        for(int j=0;j<5;j++) acc[j] += gx*CJ[k][j] - gy*SJ[k][j];
      }
      #pragma unroll
      for(int j=0;j<5;j++){
        int t = tg*5 + j;
        float a = acc[j];
        const float* vrow = vb + t*32;
        #pragma unroll
        for(int c4=0;c4<WID;c4+=4){
          float4 vv = *(const float4*)(vrow + c4);   // broadcast b128
          a += vv.x*wreg[c4] + vv.y*wreg[c4+1] + vv.z*wreg[c4+2] + vv.w*wreg[c4+3];
        }
        outp[t*32 + oid] = GELU ? gelu_f(a) : a;     // lanes 0-31: one full 128B line
      }
    }
  }
}

// ---------------- fused fc1+gelu+fc2: V -> out [B,X,Y,T,2] ----------------
__global__ __launch_bounds__(256) void k_mlp(const float* __restrict__ V, const float* __restrict__ w1,
                                             const float* __restrict__ b1, const float* __restrict__ w2,
                                             const float* __restrict__ b2, float* __restrict__ out){
  __shared__ float sw1t[64*WID];          // [j][c]
  __shared__ float sb1[64], sw2[128], sb2[2];
  int tid=threadIdx.x;
  for(int i=tid;i<64*WID;i+=256){ int j=i>>5, c=i&31; sw1t[i]=w1[c*64+j]; }
  if(tid<64) sb1[tid]=b1[tid];
  if(tid<128) sw2[tid]=w2[tid];
  if(tid<2) sb2[tid]=b2[tid];
  __syncthreads();
  size_t p0 = (size_t)blockIdx.x*1024 + (size_t)tid*4;
  float vv[128];
  const float4* vp = (const float4*)(V + p0*WID);
  #pragma unroll
  for(int q=0;q<32;q++) *((float4*)(vv+4*q)) = vp[q];
  float oa[8];
  #pragma unroll
  for(int pt=0;pt<4;pt++){ oa[2*pt]=sb2[0]; oa[2*pt+1]=sb2[1]; }
  #pragma unroll 4
  for(int j=0;j<64;j++){
    float a0=sb1[j], a1=a0, a2=a0, a3=a0;
    const float* wrow = sw1t + j*WID;
    #pragma unroll
    for(int c4=0;c4<WID;c4+=4){
      float4 w = *(const float4*)(wrow + c4);        // broadcast b128
      a0 += vv[     c4]*w.x + vv[     c4+1]*w.y + vv[     c4+2]*w.z + vv[     c4+3]*w.w;
      a1 += vv[32 + c4]*w.x + vv[32 + c4+1]*w.y + vv[32 + c4+2]*w.z + vv[32 + c4+3]*w.w;
      a2 += vv[64 + c4]*w.x + vv[64 + c4+1]*w.y + vv[64 + c4+2]*w.z + vv[64 + c4+3]*w.w;
      a3 += vv[96 + c4]*w.x + vv[96 + c4+1]*w.y + vv[96 + c4+2]*w.z + vv[96 + c4+3]*w.w;
    }
    a0=gelu_f(a0); a1=gelu_f(a1); a2=gelu_f(a2); a3=gelu_f(a3);
    float u0=sw2[2*j], u1=sw2[2*j+1];
    oa[0]+=a0*u0; oa[1]+=a0*u1; oa[2]+=a1*u0; oa[3]+=a1*u1;
    oa[4]+=a2*u0; oa[5]+=a2*u1; oa[6]+=a3*u0; oa[7]+=a3*u1;
  }
  float4* op = (float4*)(out + p0*2);
  op[0]=make_float4(oa[0],oa[1],oa[2],oa[3]);
  op[1]=make_float4(oa[4],oa[5],oa[6],oa[7]);
}

extern "C" void kernel_launch(void* const* d_in, const int* in_sizes, int n_in,
                              void* d_out, int out_size, void* d_ws, size_t ws_size,
                              hipStream_t stream){
  const float* h     = (const float*)d_in[0];
  const float* x     = (const float*)d_in[1];
  const float* fc0_w = (const float*)d_in[2];
  const float* fc0_b = (const float*)d_in[3];
  const float* scwr[3] = {(const float*)d_in[4], (const float*)d_in[6], (const float*)d_in[8]};
  const float* scwi[3] = {(const float*)d_in[5], (const float*)d_in[7], (const float*)d_in[9]};
  const float* cw[3]   = {(const float*)d_in[10], (const float*)d_in[12], (const float*)d_in[14]};
  const float* cb[3]   = {(const float*)d_in[11], (const float*)d_in[13], (const float*)d_in[15]};
  const float* fc1_w = (const float*)d_in[16];
  const float* fc1_b = (const float*)d_in[17];
  const float* fc2_w = (const float*)d_in[18];
  const float* fc2_b = (const float*)d_in[19];

  // workspace: V (167.8 MB, layout [b,x,y,t,c]) | F2 (25.2 MB) | F4 (9.4 MB)
  // F3 lives in d_out (9.4 MB <= 10.5 MB) until k_mlp overwrites it.
  const size_t VSZ = (size_t)BATCH*WID*NXYT;
  float*  V  = (float*)d_ws;
  float2* F2 = (float2*)(V + VSZ);
  float2* F4 = F2 + (size_t)BATCH*WID*NX*KYC*KT;
  float2* F3 = (float2*)d_out;

  k_fc0<<<NP/32, 256, 0, stream>>>(h, x, fc0_w, fc0_b, V);
  for(int L=0; L<3; L++){
    k_fwd_ty<<<BATCH*NX*2, 256, 0, stream>>>(V, F2);
    k_fwd_x<<<(BATCH*WID)*KYC, 256, 0, stream>>>(F2, F3);
    k_mix<<<KXC*KYC, 256, 0, stream>>>(F3, scwr[L], scwi[L], F4);
    k_inv_x<<<(BATCH*WID)*KYC, 256, 0, stream>>>(F4, F2);
    if(L<2) k_conv<true ><<<BATCH*NX*2, 256, 0, stream>>>(F2, cw[L], cb[L], V);
    else    k_conv<false><<<BATCH*NX*2, 256, 0, stream>>>(F2, cw[L], cb[L], V);
  }
  k_mlp<<<NP/1024, 256, 0, stream>>>(V, fc1_w, fc1_b, fc2_w, fc2_b, (float*)d_out);
}

// Round 4
// 1402.179 us; speedup vs baseline: 1.1431x; 1.1431x over previous
//
#include <hip/hip_runtime.h>
#include <math.h>

#define BATCH 8
#define WID   32
#define NX    64
#define NY    64
#define NT    40
#define M1C   12
#define KT    8      // M3
#define KXC   24
#define KYC   24
#define NXY   (NX*NY)        // 4096
#define NXYT  (NXY*NT)       // 163840
#define NP    (BATCH*NXYT)   // 1310720

#define TWO_PI 6.283185307179586f

static __device__ __forceinline__ float gelu_f(float v){
  return 0.5f*v*(1.0f + erff(v*0.7071067811865476f));
}

// barrier that does NOT drain vmcnt (keeps global prefetch loads in flight).
static __device__ __forceinline__ void barrier_lds(){
  asm volatile("s_waitcnt lgkmcnt(0)\n\ts_barrier" ::: "memory");
}

// V layout throughout: [b][x][y][t][c]  (channel-innermost, plane = 1280 floats)

// ---------------- fc0: [B,X,Y,T,5] -> V ----------------
__global__ __launch_bounds__(256) void k_fc0(const float* __restrict__ h, const float* __restrict__ x,
                                             const float* __restrict__ w, const float* __restrict__ b,
                                             float* __restrict__ V){
  __shared__ float sw[160], sb[32];
  int tid=threadIdx.x;
  if(tid<160) sw[tid]=w[tid];
  if(tid<32)  sb[tid]=b[tid];
  __syncthreads();
  int pl = tid>>3, q = tid&7;
  int p = blockIdx.x*32 + pl;
  float i0=h[(size_t)p*2], i1=h[(size_t)p*2+1];
  float i2=x[(size_t)p*3], i3=x[(size_t)p*3+1], i4=x[(size_t)p*3+2];
  int c0=q*4;
  float4 o;
  float* po=(float*)&o;
  #pragma unroll
  for(int u=0;u<4;u++){
    int c=c0+u;
    po[u] = sb[c] + i0*sw[c] + i1*sw[32+c] + i2*sw[64+c] + i3*sw[96+c] + i4*sw[128+c];
  }
  ((float4*)V)[(size_t)p*8 + q] = o;
}

// ------- fused forward T+Y per (b,x): V slice -> F2 [bc*64+x][ky*8+kt] -------
// R9 rebuild (LDS-pipe work cut; R8's ky-split reverted — occupancy wasn't it):
//  * V staged TRANSPOSED [y][c][t] pitch 42: T-loop's 80 ds_read_b32 per 2y
//    become 20 ds_read_b64 (t contiguous per thread). dword bank = (10c+t)%32
//    -> 2-way aliasing = free, both read & write side.
//  * radix-2 folded into STAGING: store u=v[t]+v[t+20] at tslot t and
//    d=v[t]-v[t+20] at tslot 20+t; thread k reads only its parity half
//    (e^{-2pi i k(t+20)/40} = (-1)^k e^{-2pi i kt/40}), twr shrinks to 20.
//  * 4-y groups double-buffered with register prefetch (k_conv-style):
//    ONE lgkm-only barrier per group (16/dispatch vs 32), HBM latency hidden.
__global__ __launch_bounds__(256) void k_fwd_ty(const float* __restrict__ V, float2* __restrict__ F2){
  __shared__ __align__(16) unsigned char smem[55296];
  float*  vt0   = (float*)smem;                 // [4y][32c][42] = 21504 B
  float*  vt1   = (float*)(smem+21504);         // 21504 B
  float2* twy   = (float2*)(smem+43008);        // [24][64] = 12288 B (end 55296)
  float2* f2out = (float2*)smem;                // epilogue alias: 32*193*8 = 49408 B
  int tid = threadIdx.x;
  int b = blockIdx.x >> 6, x = blockIdx.x & 63;
  int c = tid & 31, k = tid >> 5;
  for(int i=tid;i<KYC*NY;i+=256){
    int ky=i>>6, y=i&63;
    int f = ky<M1C ? ky : ky+40;
    float ang = -TWO_PI*(float)((f*y)%NY)/(float)NY;
    twy[i] = make_float2(cosf(ang), sinf(ang));
  }
  // per-thread T-twiddle HALF-row (radix-2)
  float2 twr[20];
  #pragma unroll
  for(int t=0;t<20;t++){
    float ang = -TWO_PI*(float)((k*t)%NT)/(float)NT;
    twr[t] = make_float2(cosf(ang), sinf(ang));
  }
  int toff = (k&1)*20;                     // even k -> u half, odd k -> d half
  float2 acc[KYC];
  #pragma unroll
  for(int q=0;q<KYC;q++) acc[q]=make_float2(0.f,0.f);
  const float4* src = (const float4*)(V + (size_t)(b*NX+x)*(NY*NT*WID));

  // staging slots: s in [0,640) = [y 4][t 20][c4 8]; each slot loads the
  // (t, t+20) float4 pair and writes butterfly results u/d (8 b32, 2-way banks)
  float4 pa[3], pb[3];
  #pragma unroll
  for(int i=0;i<3;i++){
    int s = tid + i*256;
    if(s<640){
      int c4=s&7, t=(s>>3)%20, y=s/160;
      pa[i] = src[y*320 + t*8 + c4];
      pb[i] = src[y*320 + t*8 + c4 + 160];
    }
  }
  #pragma unroll
  for(int i=0;i<3;i++){
    int s = tid + i*256;
    if(s<640){
      int c4=s&7, t=(s>>3)%20, y=s/160;
      float* bse = vt0 + y*1344 + t;
      #pragma unroll
      for(int e=0;e<4;e++){
        float av=((float*)&pa[i])[e], bv=((float*)&pb[i])[e];
        bse[(4*c4+e)*42]      = av+bv;
        bse[(4*c4+e)*42 + 20] = av-bv;
      }
    }
  }
  #pragma unroll
  for(int i=0;i<3;i++){                    // prefetch group 1
    int s = tid + i*256;
    if(s<640){
      int c4=s&7, t=(s>>3)%20, y=s/160;
      pa[i] = src[1280 + y*320 + t*8 + c4];
      pb[i] = src[1280 + y*320 + t*8 + c4 + 160];
    }
  }
  __syncthreads();                         // vt0 + twy visible

  #pragma unroll 1
  for(int g=0; g<16; ++g){
    const float* vb = (g&1) ? vt1 : vt0;
    float* vn       = (g&1) ? vt0 : vt1;
    if(g+1<16){                            // stage group g+1 (regs -> vn)
      #pragma unroll
      for(int i=0;i<3;i++){
        int s = tid + i*256;
        if(s<640){
          int c4=s&7, t=(s>>3)%20, y=s/160;
          float* bse = vn + y*1344 + t;
          #pragma unroll
          for(int e=0;e<4;e++){
            float av=((float*)&pa[i])[e], bv=((float*)&pb[i])[e];
            bse[(4*c4+e)*42]      = av+bv;
            bse[(4*c4+e)*42 + 20] = av-bv;
          }
        }
      }
      if(g+2<16){                          // issue loads for group g+2
        const float4* sg = src + (size_t)(g+2)*1280;
        #pragma unroll
        for(int i=0;i<3;i++){
          int s = tid + i*256;
          if(s<640){
            int c4=s&7, t=(s>>3)%20, y=s/160;
            pa[i] = sg[y*320 + t*8 + c4];
            pb[i] = sg[y*320 + t*8 + c4 + 160];
          }
        }
      }
    }
    #pragma unroll
    for(int yl=0; yl<4; yl+=2){
      const float* vp0 = vb + yl*1344 + c*42 + toff;
      const float* vp1 = vp0 + 1344;
      float sr0=0.f,si0=0.f,sr1=0.f,si1=0.f;
      #pragma unroll
      for(int it=0; it<5; it++){
        float2 a0 = *(const float2*)(vp0 + it*4);
        float2 b0 = *(const float2*)(vp0 + it*4 + 2);
        float2 a1 = *(const float2*)(vp1 + it*4);
        float2 b1 = *(const float2*)(vp1 + it*4 + 2);
        float2 w0=twr[it*4], w1=twr[it*4+1], w2=twr[it*4+2], w3=twr[it*4+3];
        sr0 += a0.x*w0.x + a0.y*w1.x + b0.x*w2.x + b0.y*w3.x;
        si0 += a0.x*w0.y + a0.y*w1.y + b0.x*w2.y + b0.y*w3.y;
        sr1 += a1.x*w0.x + a1.y*w1.x + b1.x*w2.x + b1.y*w3.x;
        si1 += a1.x*w0.y + a1.y*w1.y + b1.x*w2.y + b1.y*w3.y;
      }
      int y = g*4 + yl;
      #pragma unroll
      for(int q=0;q<KYC;q++){
        float4 wy = *(const float4*)&twy[q*NY + y];   // (w_y, w_{y+1}) broadcast
        acc[q].x += sr0*wy.x - si0*wy.y + sr1*wy.z - si1*wy.w;
        acc[q].y += sr0*wy.y + si0*wy.x + sr1*wy.w + si1*wy.z;
      }
    }
    barrier_lds();                         // one barrier per 4-y group
  }
  // epilogue: buffers dead -> f2out alias safe (last barrier covers all waves)
  #pragma unroll
  for(int q=0;q<KYC;q++) f2out[c*193 + q*8 + k] = acc[q];
  __syncthreads();
  for(int i=tid;i<WID*KYC*KT;i+=256){
    int cc=i/192, e=i-cc*192;
    F2[((size_t)(b*WID+cc)*NX + x)*(KYC*KT) + e] = f2out[cc*193 + e];
  }
}

// ---------------- forward X: F2 -> F3 [B,32,24,24,8] cplx ----------------
__global__ __launch_bounds__(256) void k_fwd_x(const float2* __restrict__ F2, float2* __restrict__ F3){
  __shared__ float2 tile[NX*KT];
  __shared__ float2 twi[KXC*65];          // stride 65 cplx
  int tid=threadIdx.x;
  int bc = blockIdx.x / KYC;
  int ky = blockIdx.x - bc*KYC;
  for(int i=tid;i<NX*KT;i+=256){
    int xx=i/KT, kt=i-xx*KT;
    tile[i] = F2[((size_t)bc*NX + xx)*(KYC*KT) + ky*KT + kt];
  }
  for(int i=tid;i<KXC*NX;i+=256){
    int kx=i/NX, xx=i-kx*NX;
    int f = kx<M1C ? kx : kx+40;
    float ang = -TWO_PI*(float)((f*xx)%NX)/(float)NX;
    twi[kx*65+xx] = make_float2(cosf(ang), sinf(ang));
  }
  __syncthreads();
  for(int item=tid; item<KXC*KT; item+=256){
    int kx=item/KT, kt=item-kx*KT;
    float sr=0.f, si=0.f;
    #pragma unroll 8
    for(int xx=0;xx<NX;xx++){
      float2 a = tile[xx*KT+kt];
      float2 w = twi[kx*65+xx];
      sr += a.x*w.x - a.y*w.y;
      si += a.x*w.y + a.y*w.x;
    }
    F3[(size_t)bc*(KXC*KYC*KT) + kx*(KYC*KT) + ky*KT + kt] = make_float2(sr,si);
  }
}

// ---------------- channel mix: F3 -> F4 ----------------
__global__ __launch_bounds__(256) void k_mix(const float2* __restrict__ F3, const float* __restrict__ wr,
                                             const float* __restrict__ wi, float2* __restrict__ F4){
  __shared__ float2 f3s[BATCH*WID*KT];     // [b][i][kt] = 16 KB
  int tid = threadIdx.x;
  int kx = blockIdx.x / KYC, ky = blockIdx.x - kx*KYC;
  int mode0 = blockIdx.x * KT;
  int xp = (kx>=M1C), yp = (ky>=M1C);
  int m1 = kx - M1C*xp, m2 = ky - M1C*yp;
  int blk = xp + 2*yp;
  for(int i=tid;i<1024;i+=256){
    int row=i>>2, q=i&3;
    ((float4*)f3s)[row*4+q] = ((const float4*)(F3 + (size_t)row*4608 + mode0))[q];
  }
  int o = tid>>3, kt = tid&7;
  size_t wbase = (size_t)blk*1179648 + (size_t)o*1152 + m1*96 + m2*8 + kt;
  float wre[WID], wim[WID];
  #pragma unroll
  for(int i=0;i<WID;i++){
    wre[i] = wr[wbase + (size_t)i*36864];
    wim[i] = wi[wbase + (size_t)i*36864];
  }
  __syncthreads();
  #pragma unroll
  for(int b=0;b<BATCH;b++){
    float ar=0.f, ai=0.f;
    #pragma unroll
    for(int i=0;i<WID;i++){
      float2 a = f3s[(b*WID+i)*KT + kt];
      ar += a.x*wre[i] - a.y*wim[i];
      ai += a.x*wim[i] + a.y*wre[i];
    }
    F4[(size_t)(b*WID+o)*4608 + mode0 + kt] = make_float2(ar,ai);
  }
}

// ---------------- inverse X: F4 -> F2 (1/64 folded) ----------------
__global__ __launch_bounds__(256) void k_inv_x(const float2* __restrict__ F4, float2* __restrict__ F2){
  __shared__ float2 tile[KXC*KT];
  __shared__ float2 twi[NX*25];
  int tid=threadIdx.x;
  int bc = blockIdx.x / KYC, ky = blockIdx.x - (blockIdx.x/KYC)*KYC;
  for(int i=tid;i<KXC*KT;i+=256){
    int kx=i/KT, kt=i-kx*KT;
    tile[i] = F4[(size_t)bc*4608 + kx*(KYC*KT) + ky*KT + kt];
  }
  for(int i=tid;i<NX*KXC;i+=256){
    int xx=i/KXC, kx=i-xx*KXC;
    int f = kx<M1C ? kx : kx+40;
    float ang = TWO_PI*(float)((f*xx)%NX)/(float)NX;
    twi[xx*25+kx] = make_float2(cosf(ang)*(1.0f/64.0f), sinf(ang)*(1.0f/64.0f));
  }
  __syncthreads();
  for(int item=tid; item<NX*KT; item+=256){
    int xx=item/KT, kt=item-xx*KT;
    float sr=0.f, si=0.f;
    #pragma unroll 8
    for(int kx=0;kx<KXC;kx++){
      float2 a = tile[kx*KT+kt];
      float2 w = twi[xx*25+kx];
      sr += a.x*w.x - a.y*w.y;
      si += a.x*w.y + a.y*w.x;
    }
    F2[((size_t)bc*NX + xx)*(KYC*KT) + ky*KT + kt] = make_float2(sr,si);
  }
}

// ------- fused inv-Y + irfft-T + conv1x1 [+gelu], in-place on V -------
// grid = B*NX*2, block = (b, x, y-half). NOTE: no min-waves clamp — the kernel
// needs ~110 VGPRs (fr[24]c + wreg[32] + 2-deep prefetch); clamping forced
// VGPR=64 and spilled fr/wreg to scratch (R3-R5 bug).
// R6/R7 established: wall is NOT VALU count / LDS count / barrier count;
// grid-capped at 4 blocks/CU, latency-bound. Left as-is (R7 schedule).
template<bool GELU>
__global__ __launch_bounds__(256) void k_conv(const float2* __restrict__ F2, const float* __restrict__ wcv,
                                              const float* __restrict__ bcv, float* __restrict__ V){
  __shared__ __align__(16) unsigned char smem[34816];
  float*  vtA  = (float*)smem;                  // [2][1280] = 10240 B
  float*  vtB  = (float*)(smem+10240);          // [2][1280] = 10240 B
  float2* ftc0 = (float2*)(smem+20480);         // [2][256]  =  4096 B
  float2* ftc1 = (float2*)(smem+24576);         // [2][256]  =  4096 B
  float2* twy  = (float2*)(smem+28672);         // [32][24]  =  6144 B (end 34816)
  float2* f2h  = (float2*)smem;                 // prologue alias: 24576 B

  int tid=threadIdx.x;
  int b  = blockIdx.x >> 7;
  int x  = (blockIdx.x >> 1) & 63;
  int y0 = (blockIdx.x & 1) * 32;
  int cid = tid & 31, ktid = tid >> 5;   // inv-Y identity
  int oid = tid & 31, tg  = tid >> 5;    // conv identity; t = tg*5+j

  // ---- prologue: F2 slice -> registers via LDS (two halves) ----
  float2 fr[KYC];
  #pragma unroll
  for(int half=0; half<2; half++){
    for(int i=tid;i<1536;i+=256){
      int cc=i/96, q=i-cc*96;
      ((float4*)f2h)[i] = *((const float4*)(F2 + ((size_t)(b*WID + half*16 + cc)*NX + x)*(KYC*KT)) + q);
    }
    __syncthreads();
    if((cid>>4) == half){
      const float2* fp = f2h + (cid&15)*192 + ktid;
      #pragma unroll
      for(int ky=0;ky<KYC;ky++) fr[ky] = fp[ky*8];
    }
    __syncthreads();
  }
  // fold irfft-T scale (k==0?1:2)/NT into fr (linear through inv-Y)
  {
    float ts = (ktid==0 ? 1.0f : 2.0f) * (1.0f/(float)NT);
    #pragma unroll
    for(int ky=0;ky<KYC;ky++){ fr[ky].x *= ts; fr[ky].y *= ts; }
  }
  float wreg[WID];
  #pragma unroll
  for(int cc=0;cc<WID;cc++) wreg[cc] = wcv[oid*WID + cc];
  float breg = bcv[oid];
  // per-thread T-twiddle base: e^{i*pi/4*(k*tg mod 8)}  (t = 5*tg + j)
  float2 twtg[KT];
  #pragma unroll
  for(int k=0;k<KT;k++){
    float ang = 0.78539816339744831f*(float)((k*tg)&7);
    twtg[k] = make_float2(cosf(ang), sinf(ang));
  }
  for(int i=tid;i<32*KYC;i+=256){
    int yy=i/KYC, ky=i-yy*KYC;
    int f = ky<M1C ? ky : ky+40;
    float ang = TWO_PI*(float)((f*(y0+yy))%NY)/(float)NY;
    twy[i] = make_float2(cosf(ang)*(1.0f/64.0f), sinf(ang)*(1.0f/64.0f));
  }
  float* plane = V + (size_t)((b*NX+x)*NY + y0)*(NT*WID);
  const float4* gp = (const float4*)plane;
  bool has3 = tid < 128;
  // stage pair 0 into vtA
  {
    float4 p0 = gp[tid], p1 = gp[256+tid];
    float4 p2 = has3 ? gp[512+tid] : make_float4(0,0,0,0);
    ((float4*)vtA)[tid] = p0;
    ((float4*)vtA)[256+tid] = p1;
    if(has3) ((float4*)vtA)[512+tid] = p2;
  }
  // pair 1 -> registers (stays in flight across the prologue barrier's drain)
  float4 rA = gp[640+tid], rB = gp[640+256+tid];
  float4 rC = has3 ? gp[640+512+tid] : make_float4(0,0,0,0);
  __syncthreads();                        // publish vtA + twy (prologue only)

  // cos/sin(pi*k*j/20) — compile-time literals (fold into v_fmac immediates)
  constexpr float CJ[KT][5] = {
    {1.f, 1.f,          1.f,          1.f,          1.f         },
    {1.f, 0.98768834f,  0.95105652f,  0.89100652f,  0.80901699f },
    {1.f, 0.95105652f,  0.80901699f,  0.58778525f,  0.30901699f },
    {1.f, 0.89100652f,  0.58778525f,  0.15643447f, -0.30901699f },
    {1.f, 0.80901699f,  0.30901699f, -0.30901699f, -0.80901699f },
    {1.f, 0.70710678f,  0.f,         -0.70710678f, -1.f         },
    {1.f, 0.58778525f, -0.30901699f, -0.95105652f, -0.80901699f },
    {1.f, 0.45399050f, -0.58778525f, -0.98768834f, -0.30901699f },
  };
  constexpr float SJ[KT][5] = {
    {0.f, 0.f,          0.f,          0.f,          0.f         },
    {0.f, 0.15643447f,  0.30901699f,  0.45399050f,  0.58778525f },
    {0.f, 0.30901699f,  0.58778525f,  0.80901699f,  0.95105652f },
    {0.f, 0.45399050f,  0.80901699f,  0.98768834f,  0.95105652f },
    {0.f, 0.58778525f,  0.95105652f,  0.95105652f,  0.58778525f },
    {0.f, 0.70710678f,  1.f,          0.70710678f,  0.f         },
    {0.f, 0.80901699f,  0.95105652f,  0.30901699f, -0.58778525f },
    {0.f, 0.89100652f,  0.80901699f, -0.15643447f, -0.95105652f },
  };

  #pragma unroll 1
  for(int it=0; it<16; ++it){
    float*  vcur = (it&1) ? vtB  : vtA;
    float*  vnxt = (it&1) ? vtA  : vtB;
    float2* fcur = (it&1) ? ftc1 : ftc0;
    int yl = it*2;
    { // inverse-Y for y=yl and yl+1, interleaved chains, b128 ky-pair twiddles
      const float2* tw0 = twy + (size_t)yl*KYC;
      const float2* tw1 = tw0 + KYC;
      float sr0=0.f, si0=0.f, sr1=0.f, si1=0.f;
      #pragma unroll
      for(int ky=0;ky<KYC;ky+=2){
        float2 a  = fr[ky];
        float2 b2 = fr[ky+1];
        float4 w0 = *(const float4*)&tw0[ky];
        float4 w1 = *(const float4*)&tw1[ky];
        sr0 += a.x*w0.x - a.y*w0.y + b2.x*w0.z - b2.y*w0.w;
        si0 += a.x*w0.y + a.y*w0.x + b2.x*w0.w + b2.y*w0.z;
        sr1 += a.x*w1.x - a.y*w1.y + b2.x*w1.z - b2.y*w1.w;
        si1 += a.x*w1.y + a.y*w1.x + b2.x*w1.w + b2.y*w1.z;
      }
      fcur[      ktid*32 + cid] = make_float2(sr0,si0);
      fcur[256 + ktid*32 + cid] = make_float2(sr1,si1);
    }
    barrier_lds();                        // the ONLY barrier per iteration
    // stage pair it+1 (regs -> vnxt) BEFORE this iteration's stores; the
    // vmcnt wait here only drains rA/rB/rC (issued a full iteration ago).
    if(it+1 < 16){
      ((float4*)vnxt)[tid] = rA;
      ((float4*)vnxt)[256+tid] = rB;
      if(has3) ((float4*)vnxt)[512+tid] = rC;
    }
    if(it+2 < 16){                        // issue loads for pair it+2
      const float4* q = gp + (size_t)(it+2)*640;
      rA = q[tid]; rB = q[256+tid];
      if(has3) rC = q[512+tid];
    }
    #pragma unroll
    for(int yy=0; yy<2; yy++){            // conv1x1 + irfft-T for the two y
      const float2* fsrc = fcur + yy*256;
      const float*  vb   = vcur + yy*1280;
      float* outp = plane + (size_t)(yl+yy)*(NT*WID);
      float acc[5];
      #pragma unroll
      for(int j=0;j<5;j++) acc[j] = breg;
      #pragma unroll
      for(int k=0;k<KT;k++){              // rotate mode by twtg, then literal DFT
        float2 f = fsrc[k*32 + oid];
        float gx = f.x*twtg[k].x - f.y*twtg[k].y;
        float gy = f.x*twtg[k].y + f.y*twtg[k].x;
        #pragma unroll
        for(int j=0;j<5;j++) acc[j] += gx*CJ[k][j] - gy*SJ[k][j];
      }
      #pragma unroll
      for(int j=0;j<5;j++){
        int t = tg*5 + j;
        float a = acc[j];
        const float* vrow = vb + t*32;
        #pragma unroll
        for(int c4=0;c4<WID;c4+=4){
          float4 vv = *(const float4*)(vrow + c4);   // broadcast b128
          a += vv.x*wreg[c4] + vv.y*wreg[c4+1] + vv.z*wreg[c4+2] + vv.w*wreg[c4+3];
        }
        outp[t*32 + oid] = GELU ? gelu_f(a) : a;     // lanes 0-31: one full 128B line
      }
    }
  }
}

// ---------------- fused fc1+gelu+fc2: V -> out [B,X,Y,T,2] ----------------
__global__ __launch_bounds__(256) void k_mlp(const float* __restrict__ V, const float* __restrict__ w1,
                                             const float* __restrict__ b1, const float* __restrict__ w2,
                                             const float* __restrict__ b2, float* __restrict__ out){
  __shared__ float sw1t[64*WID];          // [j][c]
  __shared__ float sb1[64], sw2[128], sb2[2];
  int tid=threadIdx.x;
  for(int i=tid;i<64*WID;i+=256){ int j=i>>5, c=i&31; sw1t[i]=w1[c*64+j]; }
  if(tid<64) sb1[tid]=b1[tid];
  if(tid<128) sw2[tid]=w2[tid];
  if(tid<2) sb2[tid]=b2[tid];
  __syncthreads();
  size_t p0 = (size_t)blockIdx.x*1024 + (size_t)tid*4;
  float vv[128];
  const float4* vp = (const float4*)(V + p0*WID);
  #pragma unroll
  for(int q=0;q<32;q++) *((float4*)(vv+4*q)) = vp[q];
  float oa[8];
  #pragma unroll
  for(int pt=0;pt<4;pt++){ oa[2*pt]=sb2[0]; oa[2*pt+1]=sb2[1]; }
  #pragma unroll 4
  for(int j=0;j<64;j++){
    float a0=sb1[j], a1=a0, a2=a0, a3=a0;
    const float* wrow = sw1t + j*WID;
    #pragma unroll
    for(int c4=0;c4<WID;c4+=4){
      float4 w = *(const float4*)(wrow + c4);        // broadcast b128
      a0 += vv[     c4]*w.x + vv[     c4+1]*w.y + vv[     c4+2]*w.z + vv[     c4+3]*w.w;
      a1 += vv[32 + c4]*w.x + vv[32 + c4+1]*w.y + vv[32 + c4+2]*w.z + vv[32 + c4+3]*w.w;
      a2 += vv[64 + c4]*w.x + vv[64 + c4+1]*w.y + vv[64 + c4+2]*w.z + vv[64 + c4+3]*w.w;
      a3 += vv[96 + c4]*w.x + vv[96 + c4+1]*w.y + vv[96 + c4+2]*w.z + vv[96 + c4+3]*w.w;
    }
    a0=gelu_f(a0); a1=gelu_f(a1); a2=gelu_f(a2); a3=gelu_f(a3);
    float u0=sw2[2*j], u1=sw2[2*j+1];
    oa[0]+=a0*u0; oa[1]+=a0*u1; oa[2]+=a1*u0; oa[3]+=a1*u1;
    oa[4]+=a2*u0; oa[5]+=a2*u1; oa[6]+=a3*u0; oa[7]+=a3*u1;
  }
  float4* op = (float4*)(out + p0*2);
  op[0]=make_float4(oa[0],oa[1],oa[2],oa[3]);
  op[1]=make_float4(oa[4],oa[5],oa[6],oa[7]);
}

extern "C" void kernel_launch(void* const* d_in, const int* in_sizes, int n_in,
                              void* d_out, int out_size, void* d_ws, size_t ws_size,
                              hipStream_t stream){
  const float* h     = (const float*)d_in[0];
  const float* x     = (const float*)d_in[1];
  const float* fc0_w = (const float*)d_in[2];
  const float* fc0_b = (const float*)d_in[3];
  const float* scwr[3] = {(const float*)d_in[4], (const float*)d_in[6], (const float*)d_in[8]};
  const float* scwi[3] = {(const float*)d_in[5], (const float*)d_in[7], (const float*)d_in[9]};
  const float* cw[3]   = {(const float*)d_in[10], (const float*)d_in[12], (const float*)d_in[14]};
  const float* cb[3]   = {(const float*)d_in[11], (const float*)d_in[13], (const float*)d_in[15]};
  const float* fc1_w = (const float*)d_in[16];
  const float* fc1_b = (const float*)d_in[17];
  const float* fc2_w = (const float*)d_in[18];
  const float* fc2_b = (const float*)d_in[19];

  // workspace: V (167.8 MB, layout [b,x,y,t,c]) | F2 (25.2 MB) | F4 (9.4 MB)
  // F3 lives in d_out (9.4 MB <= 10.5 MB) until k_mlp overwrites it.
  const size_t VSZ = (size_t)BATCH*WID*NXYT;
  float*  V  = (float*)d_ws;
  float2* F2 = (float2*)(V + VSZ);
  float2* F4 = F2 + (size_t)BATCH*WID*NX*KYC*KT;
  float2* F3 = (float2*)d_out;

  k_fc0<<<NP/32, 256, 0, stream>>>(h, x, fc0_w, fc0_b, V);
  for(int L=0; L<3; L++){
    k_fwd_ty<<<BATCH*NX, 256, 0, stream>>>(V, F2);
    k_fwd_x<<<(BATCH*WID)*KYC, 256, 0, stream>>>(F2, F3);
    k_mix<<<KXC*KYC, 256, 0, stream>>>(F3, scwr[L], scwi[L], F4);
    k_inv_x<<<(BATCH*WID)*KYC, 256, 0, stream>>>(F4, F2);
    if(L<2) k_conv<true ><<<BATCH*NX*2, 256, 0, stream>>>(F2, cw[L], cb[L], V);
    else    k_conv<false><<<BATCH*NX*2, 256, 0, stream>>>(F2, cw[L], cb[L], V);
  }
  k_mlp<<<NP/1024, 256, 0, stream>>>(V, fc1_w, fc1_b, fc2_w, fc2_b, (float*)d_out);
}

// Round 5
// 1392.615 us; speedup vs baseline: 1.1509x; 1.0069x over previous
//
#include <hip/hip_runtime.h>
#include <math.h>

#define BATCH 8
#define WID   32
#define NX    64
#define NY    64
#define NT    40
#define M1C   12
#define KT    8      // M3
#define KXC   24
#define KYC   24
#define NXY   (NX*NY)        // 4096
#define NXYT  (NXY*NT)       // 163840
#define NP    (BATCH*NXYT)   // 1310720

#define TWO_PI 6.283185307179586f

static __device__ __forceinline__ float gelu_f(float v){
  return 0.5f*v*(1.0f + erff(v*0.7071067811865476f));
}

// barrier that does NOT drain vmcnt (keeps global prefetch loads in flight).
static __device__ __forceinline__ void barrier_lds(){
  asm volatile("s_waitcnt lgkmcnt(0)\n\ts_barrier" ::: "memory");
}

// V layout throughout: [b][x][y][t][c]  (channel-innermost, plane = 1280 floats)

// ---------------- fc0: [B,X,Y,T,5] -> V ----------------
__global__ __launch_bounds__(256) void k_fc0(const float* __restrict__ h, const float* __restrict__ x,
                                             const float* __restrict__ w, const float* __restrict__ b,
                                             float* __restrict__ V){
  __shared__ float sw[160], sb[32];
  int tid=threadIdx.x;
  if(tid<160) sw[tid]=w[tid];
  if(tid<32)  sb[tid]=b[tid];
  __syncthreads();
  int pl = tid>>3, q = tid&7;
  int p = blockIdx.x*32 + pl;
  float i0=h[(size_t)p*2], i1=h[(size_t)p*2+1];
  float i2=x[(size_t)p*3], i3=x[(size_t)p*3+1], i4=x[(size_t)p*3+2];
  int c0=q*4;
  float4 o;
  float* po=(float*)&o;
  #pragma unroll
  for(int u=0;u<4;u++){
    int c=c0+u;
    po[u] = sb[c] + i0*sw[c] + i1*sw[32+c] + i2*sw[64+c] + i3*sw[96+c] + i4*sw[128+c];
  }
  ((float4*)V)[(size_t)p*8 + q] = o;
}

// ------- fused forward T+Y per (b,x): V slice -> F2 [bc*64+x][ky*8+kt] -------
// R10: 512-thread blocks, even/odd group split. fwd_ty ran at only 8 waves/CU
// (grid 512 = 2 blocks/CU x 4 waves) with per-SIMD issue ~6x below wall ->
// dependency-stall-bound at 2 waves/SIMD. Waves 0-3 (h=0) process even 2-y
// groups, waves 4-7 (h=1) odd groups; each half has PRIVATE double-buffered
// staging (same 55.3KB LDS, V still read exactly once - the R8 mistake was
// duplicating it). acc[24] partials merged in epilogue. 16 waves/CU now.
// Keeps R9's data path: transposed [c][t] pitch-42 staging, radix-2 butterfly
// folded into staging, b64 T-reads, register global prefetch.
__global__ __launch_bounds__(512) void k_fwd_ty(const float* __restrict__ V, float2* __restrict__ F2){
  __shared__ __align__(16) unsigned char smem[55296];
  // buf[h][p] at h*21504 + p*10752 ([2y][32c][42] = 10752 B each)
  float2* twy   = (float2*)(smem+43008);        // [24][64] = 12288 B (end 55296)
  float2* f2out = (float2*)smem;                // epilogue alias: 32*193*8 = 49408 B
  int tid = threadIdx.x;
  int h = tid >> 8, t8 = tid & 255;
  int b = blockIdx.x >> 6, x = blockIdx.x & 63;
  int c = t8 & 31, k = t8 >> 5;
  for(int i=tid;i<KYC*NY;i+=512){
    int ky=i>>6, y=i&63;
    int f = ky<M1C ? ky : ky+40;
    float ang = -TWO_PI*(float)((f*y)%NY)/(float)NY;
    twy[i] = make_float2(cosf(ang), sinf(ang));
  }
  // per-thread T-twiddle HALF-row (radix-2)
  float2 twr[20];
  #pragma unroll
  for(int t=0;t<20;t++){
    float ang = -TWO_PI*(float)((k*t)%NT)/(float)NT;
    twr[t] = make_float2(cosf(ang), sinf(ang));
  }
  float sgn = (k&1) ? -1.0f : 1.0f;
  int toff = (k&1)*20;                     // even k -> u half, odd k -> d half
  float2 acc[KYC];
  #pragma unroll
  for(int q=0;q<KYC;q++) acc[q]=make_float2(0.f,0.f);
  const float4* src = (const float4*)(V + (size_t)(b*NX+x)*(NY*NT*WID));
  float* myb0 = (float*)(smem + h*21504);
  float* myb1 = myb0 + 2688;               // +10752 B

  // staging slots for a 2-y group: s in [0,320) = [yl 2][t 20][c4 8];
  // slot s loads the (t, t+20) float4 pair, writes butterfly u/d (8 b32 each).
  int s0 = t8;                             // always active
  int c40 = s0&7, t0s = (s0>>3)%20, yl0 = s0/160;
  bool has1 = (t8 < 64);                   // s1 = t8+256 in [256,320)
  int s1 = t8 + 256;
  int c41 = s1&7, t1s = (s1>>3)%20, yl1 = s1/160;

  float4 pa0, pb0, pa1, pb1;
  // ---- prologue: group g=h -> myb0 ----
  pa0 = src[(2*h + yl0)*320 + t0s*8 + c40];
  pb0 = src[(2*h + yl0)*320 + t0s*8 + c40 + 160];
  if(has1){
    pa1 = src[(2*h + yl1)*320 + t1s*8 + c41];
    pb1 = src[(2*h + yl1)*320 + t1s*8 + c41 + 160];
  }
  {
    float* bse = myb0 + yl0*1344 + t0s;
    #pragma unroll
    for(int e=0;e<4;e++){
      float av=((float*)&pa0)[e], bv=((float*)&pb0)[e];
      bse[(4*c40+e)*42]      = av+bv;
      bse[(4*c40+e)*42 + 20] = av-bv;
    }
    if(has1){
      float* bs1 = myb0 + yl1*1344 + t1s;
      #pragma unroll
      for(int e=0;e<4;e++){
        float av=((float*)&pa1)[e], bv=((float*)&pb1)[e];
        bs1[(4*c41+e)*42]      = av+bv;
        bs1[(4*c41+e)*42 + 20] = av-bv;
      }
    }
  }
  // prefetch group g+2
  pa0 = src[(2*(h+2) + yl0)*320 + t0s*8 + c40];
  pb0 = src[(2*(h+2) + yl0)*320 + t0s*8 + c40 + 160];
  if(has1){
    pa1 = src[(2*(h+2) + yl1)*320 + t1s*8 + c41];
    pb1 = src[(2*(h+2) + yl1)*320 + t1s*8 + c41 + 160];
  }
  __syncthreads();                         // my buf0 + twy visible

  #pragma unroll 1
  for(int it=0; it<16; ++it){
    int g = 2*it + h;                      // h=0: even groups, h=1: odd; union = all 32
    const float* vb = (it&1) ? myb1 : myb0;
    float*       vn = (it&1) ? myb0 : myb1;
    if(it+1<16){                           // stage group g+2 (regs -> vn)
      float* bse = vn + yl0*1344 + t0s;
      #pragma unroll
      for(int e=0;e<4;e++){
        float av=((float*)&pa0)[e], bv=((float*)&pb0)[e];
        bse[(4*c40+e)*42]      = av+bv;
        bse[(4*c40+e)*42 + 20] = av-bv;
      }
      if(has1){
        float* bs1 = vn + yl1*1344 + t1s;
        #pragma unroll
        for(int e=0;e<4;e++){
          float av=((float*)&pa1)[e], bv=((float*)&pb1)[e];
          bs1[(4*c41+e)*42]      = av+bv;
          bs1[(4*c41+e)*42 + 20] = av-bv;
        }
      }
      if(it+2<16){                         // issue loads for group g+4
        const float4* sg = src + (size_t)(2*(g+4))*320;
        pa0 = sg[yl0*320 + t0s*8 + c40];
        pb0 = sg[yl0*320 + t0s*8 + c40 + 160];
        if(has1){
          pa1 = sg[yl1*320 + t1s*8 + c41];
          pb1 = sg[yl1*320 + t1s*8 + c41 + 160];
        }
      }
    }
    // compute the 2 y of group g
    {
      const float* vp0 = vb + c*42 + toff;
      const float* vp1 = vp0 + 1344;
      float sr0=0.f,si0=0.f,sr1=0.f,si1=0.f;
      #pragma unroll
      for(int i5=0; i5<5; i5++){
        float2 a0 = *(const float2*)(vp0 + i5*4);
        float2 b0 = *(const float2*)(vp0 + i5*4 + 2);
        float2 a1 = *(const float2*)(vp1 + i5*4);
        float2 b1 = *(const float2*)(vp1 + i5*4 + 2);
        float2 w0=twr[i5*4], w1=twr[i5*4+1], w2=twr[i5*4+2], w3=twr[i5*4+3];
        sr0 += a0.x*w0.x + a0.y*w1.x + b0.x*w2.x + b0.y*w3.x;
        si0 += a0.x*w0.y + a0.y*w1.y + b0.x*w2.y + b0.y*w3.y;
        sr1 += a1.x*w0.x + a1.y*w1.x + b1.x*w2.x + b1.y*w3.x;
        si1 += a1.x*w0.y + a1.y*w1.y + b1.x*w2.y + b1.y*w3.y;
      }
      int y = 2*g;                         // even -> float4 twy pair aligned
      #pragma unroll
      for(int q=0;q<KYC;q++){
        float4 wy = *(const float4*)&twy[q*NY + y];   // (w_y, w_{y+1}) broadcast
        acc[q].x += sr0*wy.x - si0*wy.y + sr1*wy.z - si1*wy.w;
        acc[q].y += sr0*wy.y + si0*wy.x + sr1*wy.w + si1*wy.z;
      }
    }
    barrier_lds();                         // one barrier per group-step (both halves in lockstep)
  }
  (void)sgn;
  // epilogue merge: buffers/twy dead after final barrier -> f2out alias safe
  if(h==0){
    #pragma unroll
    for(int q=0;q<KYC;q++) f2out[c*193 + q*8 + k] = acc[q];
  }
  __syncthreads();
  if(h==1){
    #pragma unroll
    for(int q=0;q<KYC;q++){
      float2 v = f2out[c*193 + q*8 + k];
      f2out[c*193 + q*8 + k] = make_float2(v.x+acc[q].x, v.y+acc[q].y);
    }
  }
  __syncthreads();
  for(int i=tid;i<WID*KYC*KT;i+=512){
    int cc=i/192, e=i-cc*192;
    F2[((size_t)(b*WID+cc)*NX + x)*(KYC*KT) + e] = f2out[cc*193 + e];
  }
}

// ---------------- forward X: F2 -> F3 [B,32,24,24,8] cplx ----------------
__global__ __launch_bounds__(256) void k_fwd_x(const float2* __restrict__ F2, float2* __restrict__ F3){
  __shared__ float2 tile[NX*KT];
  __shared__ float2 twi[KXC*65];          // stride 65 cplx
  int tid=threadIdx.x;
  int bc = blockIdx.x / KYC;
  int ky = blockIdx.x - bc*KYC;
  for(int i=tid;i<NX*KT;i+=256){
    int xx=i/KT, kt=i-xx*KT;
    tile[i] = F2[((size_t)bc*NX + xx)*(KYC*KT) + ky*KT + kt];
  }
  for(int i=tid;i<KXC*NX;i+=256){
    int kx=i/NX, xx=i-kx*NX;
    int f = kx<M1C ? kx : kx+40;
    float ang = -TWO_PI*(float)((f*xx)%NX)/(float)NX;
    twi[kx*65+xx] = make_float2(cosf(ang), sinf(ang));
  }
  __syncthreads();
  for(int item=tid; item<KXC*KT; item+=256){
    int kx=item/KT, kt=item-kx*KT;
    float sr=0.f, si=0.f;
    #pragma unroll 8
    for(int xx=0;xx<NX;xx++){
      float2 a = tile[xx*KT+kt];
      float2 w = twi[kx*65+xx];
      sr += a.x*w.x - a.y*w.y;
      si += a.x*w.y + a.y*w.x;
    }
    F3[(size_t)bc*(KXC*KYC*KT) + kx*(KYC*KT) + ky*KT + kt] = make_float2(sr,si);
  }
}

// ---------------- channel mix: F3 -> F4 ----------------
__global__ __launch_bounds__(256) void k_mix(const float2* __restrict__ F3, const float* __restrict__ wr,
                                             const float* __restrict__ wi, float2* __restrict__ F4){
  __shared__ float2 f3s[BATCH*WID*KT];     // [b][i][kt] = 16 KB
  int tid = threadIdx.x;
  int kx = blockIdx.x / KYC, ky = blockIdx.x - kx*KYC;
  int mode0 = blockIdx.x * KT;
  int xp = (kx>=M1C), yp = (ky>=M1C);
  int m1 = kx - M1C*xp, m2 = ky - M1C*yp;
  int blk = xp + 2*yp;
  for(int i=tid;i<1024;i+=256){
    int row=i>>2, q=i&3;
    ((float4*)f3s)[row*4+q] = ((const float4*)(F3 + (size_t)row*4608 + mode0))[q];
  }
  int o = tid>>3, kt = tid&7;
  size_t wbase = (size_t)blk*1179648 + (size_t)o*1152 + m1*96 + m2*8 + kt;
  float wre[WID], wim[WID];
  #pragma unroll
  for(int i=0;i<WID;i++){
    wre[i] = wr[wbase + (size_t)i*36864];
    wim[i] = wi[wbase + (size_t)i*36864];
  }
  __syncthreads();
  #pragma unroll
  for(int b=0;b<BATCH;b++){
    float ar=0.f, ai=0.f;
    #pragma unroll
    for(int i=0;i<WID;i++){
      float2 a = f3s[(b*WID+i)*KT + kt];
      ar += a.x*wre[i] - a.y*wim[i];
      ai += a.x*wim[i] + a.y*wre[i];
    }
    F4[(size_t)(b*WID+o)*4608 + mode0 + kt] = make_float2(ar,ai);
  }
}

// ---------------- inverse X: F4 -> F2 (1/64 folded) ----------------
__global__ __launch_bounds__(256) void k_inv_x(const float2* __restrict__ F4, float2* __restrict__ F2){
  __shared__ float2 tile[KXC*KT];
  __shared__ float2 twi[NX*25];
  int tid=threadIdx.x;
  int bc = blockIdx.x / KYC, ky = blockIdx.x - (blockIdx.x/KYC)*KYC;
  for(int i=tid;i<KXC*KT;i+=256){
    int kx=i/KT, kt=i-kx*KT;
    tile[i] = F4[(size_t)bc*4608 + kx*(KYC*KT) + ky*KT + kt];
  }
  for(int i=tid;i<NX*KXC;i+=256){
    int xx=i/KXC, kx=i-xx*KXC;
    int f = kx<M1C ? kx : kx+40;
    float ang = TWO_PI*(float)((f*xx)%NX)/(float)NX;
    twi[xx*25+kx] = make_float2(cosf(ang)*(1.0f/64.0f), sinf(ang)*(1.0f/64.0f));
  }
  __syncthreads();
  for(int item=tid; item<NX*KT; item+=256){
    int xx=item/KT, kt=item-xx*KT;
    float sr=0.f, si=0.f;
    #pragma unroll 8
    for(int kx=0;kx<KXC;kx++){
      float2 a = tile[kx*KT+kt];
      float2 w = twi[xx*25+kx];
      sr += a.x*w.x - a.y*w.y;
      si += a.x*w.y + a.y*w.x;
    }
    F2[((size_t)bc*NX + xx)*(KYC*KT) + ky*KT + kt] = make_float2(sr,si);
  }
}

// ------- fused inv-Y + irfft-T + conv1x1 [+gelu], in-place on V -------
// grid = B*NX*2, block = (b, x, y-half). NOTE: no min-waves clamp — the kernel
// needs ~110 VGPRs (fr[24]c + wreg[32] + 2-deep prefetch); clamping forced
// VGPR=64 and spilled fr/wreg to scratch (R3-R5 bug).
// R6/R7 established: wall is NOT VALU count / LDS count / barrier count;
// grid-capped at 4 blocks/CU, latency-bound. Left as-is (R7 schedule).
template<bool GELU>
__global__ __launch_bounds__(256) void k_conv(const float2* __restrict__ F2, const float* __restrict__ wcv,
                                              const float* __restrict__ bcv, float* __restrict__ V){
  __shared__ __align__(16) unsigned char smem[34816];
  float*  vtA  = (float*)smem;                  // [2][1280] = 10240 B
  float*  vtB  = (float*)(smem+10240);          // [2][1280] = 10240 B
  float2* ftc0 = (float2*)(smem+20480);         // [2][256]  =  4096 B
  float2* ftc1 = (float2*)(smem+24576);         // [2][256]  =  4096 B
  float2* twy  = (float2*)(smem+28672);         // [32][24]  =  6144 B (end 34816)
  float2* f2h  = (float2*)smem;                 // prologue alias: 24576 B

  int tid=threadIdx.x;
  int b  = blockIdx.x >> 7;
  int x  = (blockIdx.x >> 1) & 63;
  int y0 = (blockIdx.x & 1) * 32;
  int cid = tid & 31, ktid = tid >> 5;   // inv-Y identity
  int oid = tid & 31, tg  = tid >> 5;    // conv identity; t = tg*5+j

  // ---- prologue: F2 slice -> registers via LDS (two halves) ----
  float2 fr[KYC];
  #pragma unroll
  for(int half=0; half<2; half++){
    for(int i=tid;i<1536;i+=256){
      int cc=i/96, q=i-cc*96;
      ((float4*)f2h)[i] = *((const float4*)(F2 + ((size_t)(b*WID + half*16 + cc)*NX + x)*(KYC*KT)) + q);
    }
    __syncthreads();
    if((cid>>4) == half){
      const float2* fp = f2h + (cid&15)*192 + ktid;
      #pragma unroll
      for(int ky=0;ky<KYC;ky++) fr[ky] = fp[ky*8];
    }
    __syncthreads();
  }
  // fold irfft-T scale (k==0?1:2)/NT into fr (linear through inv-Y)
  {
    float ts = (ktid==0 ? 1.0f : 2.0f) * (1.0f/(float)NT);
    #pragma unroll
    for(int ky=0;ky<KYC;ky++){ fr[ky].x *= ts; fr[ky].y *= ts; }
  }
  float wreg[WID];
  #pragma unroll
  for(int cc=0;cc<WID;cc++) wreg[cc] = wcv[oid*WID + cc];
  float breg = bcv[oid];
  // per-thread T-twiddle base: e^{i*pi/4*(k*tg mod 8)}  (t = 5*tg + j)
  float2 twtg[KT];
  #pragma unroll
  for(int k=0;k<KT;k++){
    float ang = 0.78539816339744831f*(float)((k*tg)&7);
    twtg[k] = make_float2(cosf(ang), sinf(ang));
  }
  for(int i=tid;i<32*KYC;i+=256){
    int yy=i/KYC, ky=i-yy*KYC;
    int f = ky<M1C ? ky : ky+40;
    float ang = TWO_PI*(float)((f*(y0+yy))%NY)/(float)NY;
    twy[i] = make_float2(cosf(ang)*(1.0f/64.0f), sinf(ang)*(1.0f/64.0f));
  }
  float* plane = V + (size_t)((b*NX+x)*NY + y0)*(NT*WID);
  const float4* gp = (const float4*)plane;
  bool has3 = tid < 128;
  // stage pair 0 into vtA
  {
    float4 p0 = gp[tid], p1 = gp[256+tid];
    float4 p2 = has3 ? gp[512+tid] : make_float4(0,0,0,0);
    ((float4*)vtA)[tid] = p0;
    ((float4*)vtA)[256+tid] = p1;
    if(has3) ((float4*)vtA)[512+tid] = p2;
  }
  // pair 1 -> registers (stays in flight across the prologue barrier's drain)
  float4 rA = gp[640+tid], rB = gp[640+256+tid];
  float4 rC = has3 ? gp[640+512+tid] : make_float4(0,0,0,0);
  __syncthreads();                        // publish vtA + twy (prologue only)

  // cos/sin(pi*k*j/20) — compile-time literals (fold into v_fmac immediates)
  constexpr float CJ[KT][5] = {
    {1.f, 1.f,          1.f,          1.f,          1.f         },
    {1.f, 0.98768834f,  0.95105652f,  0.89100652f,  0.80901699f },
    {1.f, 0.95105652f,  0.80901699f,  0.58778525f,  0.30901699f },
    {1.f, 0.89100652f,  0.58778525f,  0.15643447f, -0.30901699f },
    {1.f, 0.80901699f,  0.30901699f, -0.30901699f, -0.80901699f },
    {1.f, 0.70710678f,  0.f,         -0.70710678f, -1.f         },
    {1.f, 0.58778525f, -0.30901699f, -0.95105652f, -0.80901699f },
    {1.f, 0.45399050f, -0.58778525f, -0.98768834f, -0.30901699f },
  };
  constexpr float SJ[KT][5] = {
    {0.f, 0.f,          0.f,          0.f,          0.f         },
    {0.f, 0.15643447f,  0.30901699f,  0.45399050f,  0.58778525f },
    {0.f, 0.30901699f,  0.58778525f,  0.80901699f,  0.95105652f },
    {0.f, 0.45399050f,  0.80901699f,  0.98768834f,  0.95105652f },
    {0.f, 0.58778525f,  0.95105652f,  0.95105652f,  0.58778525f },
    {0.f, 0.70710678f,  1.f,          0.70710678f,  0.f         },
    {0.f, 0.80901699f,  0.95105652f,  0.30901699f, -0.58778525f },
    {0.f, 0.89100652f,  0.80901699f, -0.15643447f, -0.95105652f },
  };

  #pragma unroll 1
  for(int it=0; it<16; ++it){
    float*  vcur = (it&1) ? vtB  : vtA;
    float*  vnxt = (it&1) ? vtA  : vtB;
    float2* fcur = (it&1) ? ftc1 : ftc0;
    int yl = it*2;
    { // inverse-Y for y=yl and yl+1, interleaved chains, b128 ky-pair twiddles
      const float2* tw0 = twy + (size_t)yl*KYC;
      const float2* tw1 = tw0 + KYC;
      float sr0=0.f, si0=0.f, sr1=0.f, si1=0.f;
      #pragma unroll
      for(int ky=0;ky<KYC;ky+=2){
        float2 a  = fr[ky];
        float2 b2 = fr[ky+1];
        float4 w0 = *(const float4*)&tw0[ky];
        float4 w1 = *(const float4*)&tw1[ky];
        sr0 += a.x*w0.x - a.y*w0.y + b2.x*w0.z - b2.y*w0.w;
        si0 += a.x*w0.y + a.y*w0.x + b2.x*w0.w + b2.y*w0.z;
        sr1 += a.x*w1.x - a.y*w1.y + b2.x*w1.z - b2.y*w1.w;
        si1 += a.x*w1.y + a.y*w1.x + b2.x*w1.w + b2.y*w1.z;
      }
      fcur[      ktid*32 + cid] = make_float2(sr0,si0);
      fcur[256 + ktid*32 + cid] = make_float2(sr1,si1);
    }
    barrier_lds();                        // the ONLY barrier per iteration
    // stage pair it+1 (regs -> vnxt) BEFORE this iteration's stores; the
    // vmcnt wait here only drains rA/rB/rC (issued a full iteration ago).
    if(it+1 < 16){
      ((float4*)vnxt)[tid] = rA;
      ((float4*)vnxt)[256+tid] = rB;
      if(has3) ((float4*)vnxt)[512+tid] = rC;
    }
    if(it+2 < 16){                        // issue loads for pair it+2
      const float4* q = gp + (size_t)(it+2)*640;
      rA = q[tid]; rB = q[256+tid];
      if(has3) rC = q[512+tid];
    }
    #pragma unroll
    for(int yy=0; yy<2; yy++){            // conv1x1 + irfft-T for the two y
      const float2* fsrc = fcur + yy*256;
      const float*  vb   = vcur + yy*1280;
      float* outp = plane + (size_t)(yl+yy)*(NT*WID);
      float acc[5];
      #pragma unroll
      for(int j=0;j<5;j++) acc[j] = breg;
      #pragma unroll
      for(int k=0;k<KT;k++){              // rotate mode by twtg, then literal DFT
        float2 f = fsrc[k*32 + oid];
        float gx = f.x*twtg[k].x - f.y*twtg[k].y;
        float gy = f.x*twtg[k].y + f.y*twtg[k].x;
        #pragma unroll
        for(int j=0;j<5;j++) acc[j] += gx*CJ[k][j] - gy*SJ[k][j];
      }
      #pragma unroll
      for(int j=0;j<5;j++){
        int t = tg*5 + j;
        float a = acc[j];
        const float* vrow = vb + t*32;
        #pragma unroll
        for(int c4=0;c4<WID;c4+=4){
          float4 vv = *(const float4*)(vrow + c4);   // broadcast b128
          a += vv.x*wreg[c4] + vv.y*wreg[c4+1] + vv.z*wreg[c4+2] + vv.w*wreg[c4+3];
        }
        outp[t*32 + oid] = GELU ? gelu_f(a) : a;     // lanes 0-31: one full 128B line
      }
    }
  }
}

// ---------------- fused fc1+gelu+fc2: V -> out [B,X,Y,T,2] ----------------
__global__ __launch_bounds__(256) void k_mlp(const float* __restrict__ V, const float* __restrict__ w1,
                                             const float* __restrict__ b1, const float* __restrict__ w2,
                                             const float* __restrict__ b2, float* __restrict__ out){
  __shared__ float sw1t[64*WID];          // [j][c]
  __shared__ float sb1[64], sw2[128], sb2[2];
  int tid=threadIdx.x;
  for(int i=tid;i<64*WID;i+=256){ int j=i>>5, c=i&31; sw1t[i]=w1[c*64+j]; }
  if(tid<64) sb1[tid]=b1[tid];
  if(tid<128) sw2[tid]=w2[tid];
  if(tid<2) sb2[tid]=b2[tid];
  __syncthreads();
  size_t p0 = (size_t)blockIdx.x*1024 + (size_t)tid*4;
  float vv[128];
  const float4* vp = (const float4*)(V + p0*WID);
  #pragma unroll
  for(int q=0;q<32;q++) *((float4*)(vv+4*q)) = vp[q];
  float oa[8];
  #pragma unroll
  for(int pt=0;pt<4;pt++){ oa[2*pt]=sb2[0]; oa[2*pt+1]=sb2[1]; }
  #pragma unroll 4
  for(int j=0;j<64;j++){
    float a0=sb1[j], a1=a0, a2=a0, a3=a0;
    const float* wrow = sw1t + j*WID;
    #pragma unroll
    for(int c4=0;c4<WID;c4+=4){
      float4 w = *(const float4*)(wrow + c4);        // broadcast b128
      a0 += vv[     c4]*w.x + vv[     c4+1]*w.y + vv[     c4+2]*w.z + vv[     c4+3]*w.w;
      a1 += vv[32 + c4]*w.x + vv[32 + c4+1]*w.y + vv[32 + c4+2]*w.z + vv[32 + c4+3]*w.w;
      a2 += vv[64 + c4]*w.x + vv[64 + c4+1]*w.y + vv[64 + c4+2]*w.z + vv[64 + c4+3]*w.w;
      a3 += vv[96 + c4]*w.x + vv[96 + c4+1]*w.y + vv[96 + c4+2]*w.z + vv[96 + c4+3]*w.w;
    }
    a0=gelu_f(a0); a1=gelu_f(a1); a2=gelu_f(a2); a3=gelu_f(a3);
    float u0=sw2[2*j], u1=sw2[2*j+1];
    oa[0]+=a0*u0; oa[1]+=a0*u1; oa[2]+=a1*u0; oa[3]+=a1*u1;
    oa[4]+=a2*u0; oa[5]+=a2*u1; oa[6]+=a3*u0; oa[7]+=a3*u1;
  }
  float4* op = (float4*)(out + p0*2);
  op[0]=make_float4(oa[0],oa[1],oa[2],oa[3]);
  op[1]=make_float4(oa[4],oa[5],oa[6],oa[7]);
}

extern "C" void kernel_launch(void* const* d_in, const int* in_sizes, int n_in,
                              void* d_out, int out_size, void* d_ws, size_t ws_size,
                              hipStream_t stream){
  const float* h     = (const float*)d_in[0];
  const float* x     = (const float*)d_in[1];
  const float* fc0_w = (const float*)d_in[2];
  const float* fc0_b = (const float*)d_in[3];
  const float* scwr[3] = {(const float*)d_in[4], (const float*)d_in[6], (const float*)d_in[8]};
  const float* scwi[3] = {(const float*)d_in[5], (const float*)d_in[7], (const float*)d_in[9]};
  const float* cw[3]   = {(const float*)d_in[10], (const float*)d_in[12], (const float*)d_in[14]};
  const float* cb[3]   = {(const float*)d_in[11], (const float*)d_in[13], (const float*)d_in[15]};
  const float* fc1_w = (const float*)d_in[16];
  const float* fc1_b = (const float*)d_in[17];
  const float* fc2_w = (const float*)d_in[18];
  const float* fc2_b = (const float*)d_in[19];

  // workspace: V (167.8 MB, layout [b,x,y,t,c]) | F2 (25.2 MB) | F4 (9.4 MB)
  // F3 lives in d_out (9.4 MB <= 10.5 MB) until k_mlp overwrites it.
  const size_t VSZ = (size_t)BATCH*WID*NXYT;
  float*  V  = (float*)d_ws;
  float2* F2 = (float2*)(V + VSZ);
  float2* F4 = F2 + (size_t)BATCH*WID*NX*KYC*KT;
  float2* F3 = (float2*)d_out;

  k_fc0<<<NP/32, 256, 0, stream>>>(h, x, fc0_w, fc0_b, V);
  for(int L=0; L<3; L++){
    k_fwd_ty<<<BATCH*NX, 512, 0, stream>>>(V, F2);
    k_fwd_x<<<(BATCH*WID)*KYC, 256, 0, stream>>>(F2, F3);
    k_mix<<<KXC*KYC, 256, 0, stream>>>(F3, scwr[L], scwi[L], F4);
    k_inv_x<<<(BATCH*WID)*KYC, 256, 0, stream>>>(F4, F2);
    if(L<2) k_conv<true ><<<BATCH*NX*2, 256, 0, stream>>>(F2, cw[L], cb[L], V);
    else    k_conv<false><<<BATCH*NX*2, 256, 0, stream>>>(F2, cw[L], cb[L], V);
  }
  k_mlp<<<NP/1024, 256, 0, stream>>>(V, fc1_w, fc1_b, fc2_w, fc2_b, (float*)d_out);
}